// Round 2
// baseline (10919.257 us; speedup 1.0000x reference)
//
#include <hip/hip_runtime.h>

// Problem constants
constexpr int Bz = 512;   // batch
constexpr int Tz = 256;   // seq len
constexpr int Hz = 256;   // hidden
constexpr int Pz = 14;    // predict dim
constexpr int NG = 32;    // groups = blocks (16 batches each)
constexpr int BT = 16;    // batch per block
constexpr int KP = 264;   // LDS h row stride (shorts) - even bank spread (proven layout)
constexpr int XS = 260;   // x LDS row stride (floats)
constexpr int HB = BT * KP;  // shorts per h buffer (one parity)

typedef short s8v __attribute__((ext_vector_type(8)));
typedef float f4v __attribute__((ext_vector_type(4)));
typedef unsigned long long u64;

__device__ __forceinline__ short f2bf(float f) {
  unsigned u = __float_as_uint(f);
  u = (u + 0x7fffu + ((u >> 16) & 1u)) >> 16;   // RNE
  return (short)u;
}
__device__ __forceinline__ float bf2f(short s) {
  return __uint_as_float(((unsigned)(unsigned short)s) << 16);
}
// Fast gates: v_exp_f32 IS exp2; v_rcp_f32 replaces the ~10-op f32 divide.
// sigm = 1/(1+e^-v); tanh = 1 - 2/(e^{2v}+1). Saturation behaves correctly
// (exp2->inf => rcp->0). rcp is ~1ulp: far below bf16-h noise.
__device__ __forceinline__ float sigm(float v) {
  return __builtin_amdgcn_rcpf(1.0f + __builtin_amdgcn_exp2f(-1.442695041f * v));
}
__device__ __forceinline__ float tanh_f(float v) {
  return 1.0f - 2.0f * __builtin_amdgcn_rcpf(__builtin_amdgcn_exp2f(2.885390082f * v) + 1.0f);
}
__device__ __forceinline__ float unlo(unsigned u) {
  return __uint_as_float(u << 16);
}
__device__ __forceinline__ float unhi(unsigned u) {
  return __uint_as_float(u & 0xffff0000u);
}

// R11: whole-group-in-one-block. 32 blocks x 1024 threads; each block owns one
// 16-batch group and the FULL hidden dim for BOTH layers. All weight rows
// (3 x 1024 rows x 256 K, bf16) live in VGPRs: 16 waves x 12 row-tiles x 8 kt
// = 96 s8v MFMAs/wave/step. h0/h1 recurrences are block-local in LDS
// (double-buffered by step parity) -> ZERO inter-block traffic, ONE
// __syncthreads per step. This removes the ~2.7us/step LLC handshake that
// dominated R9 (800us) and sank R10 (1074us, FETCH_SIZE 1.07GB of poll spam).
//
// MFMA k-pairing: hardware pairs A elem j with B elem j within each lane
// q-group at k = kt*32 + q*8 + j (derived from the R5-proven permuted kernel:
// any common k-order on both operands is valid). So h is stored in LDS in
// PLAIN unit order and weights gather 8 CONTIGUOUS floats per fragment.
//
// Buffer parities at iter s (one barrier/iter is sufficient; every write
// parity was last read at iter s-1, i.e. across a barrier):
//   read  h0[s-1] : h0 parity (s+1)&1      write h0[s]   : parity s&1
//   read  h1[s-2] : h1 parity s&1          write h1[s-1] : parity (s+1)&1
// Lagged L1 schedule (exact, as in R5/R9): iter s computes h1[s-1] from
// input h0[s-1] and state h1[s-2]; loop runs s=0..Tz so h1[Tz-1] lands.
__global__ void __launch_bounds__(1024)
lstm2(const float* __restrict__ x,
      const float* __restrict__ w_ih0, const float* __restrict__ w_hh0,
      const float* __restrict__ b_ih0, const float* __restrict__ b_hh0,
      const float* __restrict__ w_ih1, const float* __restrict__ w_hh1,
      const float* __restrict__ b_ih1, const float* __restrict__ b_hh1,
      const float* __restrict__ w_lin, const float* __restrict__ b_lin,
      float* __restrict__ out)
{
  const int g    = blockIdx.x;
  const int tid  = threadIdx.x;
  const int w    = tid >> 6;       // wave 0..15
  const int lane = tid & 63;
  const int q    = lane >> 4;      // k-group / C row-group
  const int l15  = lane & 15;      // batch col (all 16 real)
  const int gbase = g * BT;

  extern __shared__ char smem_raw[];
  short* h0s = (short*)smem_raw;            // [2][BT][KP]
  short* h1s = h0s + 2 * HB;                // [2][BT][KP]
  float* xls = (float*)(h1s + 2 * HB);      // [BT][XS]
  float* wls = xls + BT * XS;               // [Pz][Hz] plain order

  // ---- zero-init h buffers (h0[-1], h1[-2], h1[-1] all read as 0) ----
  {
    unsigned* hz = (unsigned*)h0s;          // 4 buffers contiguous = 2*HB u32
    for (int i = tid; i < 2 * HB; i += 1024) hz[i] = 0;
  }
  // ---- x preload (16 batches x 256 steps, f32) ----
  for (int i = tid; i < BT * (Tz / 4); i += 1024) {
    int b = i >> 6, c4 = i & 63;
    *(f4v*)(xls + b * XS + c4 * 4) =
        *(const f4v*)(x + (size_t)(gbase + b) * Tz + c4 * 4);
  }
  // ---- w_lin preload (plain copy; head uses plain k order) ----
  for (int i = tid; i < Pz * Hz; i += 1024) wls[i] = w_lin[i];

  // ---- one-time: weights -> register A-fragments (contiguous k gather) ----
  // Row-tile rt = w*4+t; A-lane M-row = l15 -> rr = rt*16+l15 = unit*4+gate
  // -> weight row grow = (l15&3)*Hz + rt*4 + (l15>>2). k elems = 8 contiguous.
  s8v Wf[3][4][8];   // [mat: hh0, ih1, hh1][tile t][kt]
  {
    const float* wsrc[3] = {w_hh0, w_ih1, w_hh1};
    #pragma unroll
    for (int mat = 0; mat < 3; ++mat) {
      #pragma unroll
      for (int t = 0; t < 4; ++t) {
        int rt = w * 4 + t;
        int grow = (l15 & 3) * Hz + rt * 4 + (l15 >> 2);
        const float* p = wsrc[mat] + (size_t)grow * Hz + q * 8;
        #pragma unroll
        for (int kt = 0; kt < 8; ++kt) {
          f4v lo = *(const f4v*)(p + kt * 32);
          f4v hi = *(const f4v*)(p + kt * 32 + 4);
          s8v f;
          f[0] = f2bf(lo[0]); f[1] = f2bf(lo[1]); f[2] = f2bf(lo[2]); f[3] = f2bf(lo[3]);
          f[4] = f2bf(hi[0]); f[5] = f2bf(hi[1]); f[6] = f2bf(hi[2]); f[7] = f2bf(hi[3]);
          Wf[mat][t][kt] = f;
        }
      }
    }
  }

  // ---- per-lane epilogue constants, packed bf16 to save VGPRs ----
  // Lane (w,q) epilogue units: u(t) = 16*w + 4*t + q; gate r row = r*Hz+u.
  // |b|,|wih| <= 0.125 -> bf16 pack error ~3e-5 absolute, below bf16-h noise.
  unsigned pw[8], pb0[8], pb1[8];   // [t*2 + rpair]: lo16=gate 2rp, hi16=gate 2rp+1
  #pragma unroll
  for (int t = 0; t < 4; ++t) {
    int u = 16 * w + 4 * t + q;
    #pragma unroll
    for (int rp = 0; rp < 2; ++rp) {
      int r0 = 2 * rp, r1 = 2 * rp + 1;
      pw[t * 2 + rp]  = (unsigned)(unsigned short)f2bf(w_ih0[r0 * Hz + u])
                      | ((unsigned)(unsigned short)f2bf(w_ih0[r1 * Hz + u]) << 16);
      pb0[t * 2 + rp] = (unsigned)(unsigned short)f2bf(b_ih0[r0 * Hz + u] + b_hh0[r0 * Hz + u])
                      | ((unsigned)(unsigned short)f2bf(b_ih0[r1 * Hz + u] + b_hh0[r1 * Hz + u]) << 16);
      pb1[t * 2 + rp] = (unsigned)(unsigned short)f2bf(b_ih1[r0 * Hz + u] + b_hh1[r0 * Hz + u])
                      | ((unsigned)(unsigned short)f2bf(b_ih1[r1 * Hz + u] + b_hh1[r1 * Hz + u]) << 16);
    }
  }

  float c0[4] = {0.f, 0.f, 0.f, 0.f};   // cell states, indexed by unrolled t only
  float c1[4] = {0.f, 0.f, 0.f, 0.f};

  __syncthreads();   // prologue LDS (zeros, x, wls) visible

  for (int s = 0; s <= Tz; ++s) {
    // ---- C: fused MFMA. 16 ds_read_b128 + 96 MFMA per wave ----
    const short* H0 = h0s + ((s + 1) & 1) * HB + l15 * KP + q * 8;  // h0[s-1]
    const short* H1 = h1s + (s & 1) * HB       + l15 * KP + q * 8;  // h1[s-2]
    f4v a0[4], a1[4];
    #pragma unroll
    for (int t = 0; t < 4; ++t) { a0[t] = f4v{0.f,0.f,0.f,0.f}; a1[t] = f4v{0.f,0.f,0.f,0.f}; }
    #pragma unroll
    for (int kt = 0; kt < 8; ++kt) {
      s8v h0v = *(const s8v*)(H0 + kt * 32);
      s8v h1v = *(const s8v*)(H1 + kt * 32);
      #pragma unroll
      for (int t = 0; t < 4; ++t) {
        a0[t] = __builtin_amdgcn_mfma_f32_16x16x32_bf16(Wf[0][t][kt], h0v, a0[t], 0, 0, 0);
        a1[t] = __builtin_amdgcn_mfma_f32_16x16x32_bf16(Wf[1][t][kt], h0v, a1[t], 0, 0, 0);
        a1[t] = __builtin_amdgcn_mfma_f32_16x16x32_bf16(Wf[2][t][kt], h1v, a1[t], 0, 0, 0);
      }
    }

    // ---- D/E: in-register epilogues -> bf16 h writes to LDS ----
    short* hw0 = h0s + (s & 1) * HB;        // h0[s]
    short* hw1 = h1s + ((s + 1) & 1) * HB;  // h1[s-1]
    if (s < Tz) {
      float xv = xls[l15 * XS + s];
      #pragma unroll
      for (int t = 0; t < 4; ++t) {
        float gi = a0[t][0] + xv * unlo(pw[t*2])   + unlo(pb0[t*2]);
        float gf = a0[t][1] + xv * unhi(pw[t*2])   + unhi(pb0[t*2]);
        float gg = a0[t][2] + xv * unlo(pw[t*2+1]) + unlo(pb0[t*2+1]);
        float go = a0[t][3] + xv * unhi(pw[t*2+1]) + unhi(pb0[t*2+1]);
        float i_ = sigm(gi), f_ = sigm(gf), g_ = tanh_f(gg), o_ = sigm(go);
        c0[t] = f_ * c0[t] + i_ * g_;
        hw0[l15 * KP + 16 * w + 4 * t + q] = f2bf(o_ * tanh_f(c0[t]));
      }
    }
    if (s >= 1) {
      #pragma unroll
      for (int t = 0; t < 4; ++t) {
        float gi = a1[t][0] + unlo(pb1[t*2]);
        float gf = a1[t][1] + unhi(pb1[t*2]);
        float gg = a1[t][2] + unlo(pb1[t*2+1]);
        float go = a1[t][3] + unhi(pb1[t*2+1]);
        float i_ = sigm(gi), f_ = sigm(gf), g_ = tanh_f(gg), o_ = sigm(go);
        c1[t] = f_ * c1[t] + i_ * g_;
        hw1[l15 * KP + 16 * w + 4 * t + q] = f2bf(o_ * tanh_f(c1[t]));
      }
    }

    __syncthreads();   // write visibility for next iter (WAR spans this too)
  }

  // ---- head: out = h1[Tz-1] @ w_lin^T + b_lin ; h1[255] at parity 1 ----
  if (tid < BT * Pz) {
    int b = tid / Pz, p = tid - b * Pz;
    const short* hb = h1s + HB + b * KP;
    const float* wr = wls + p * Hz;
    float acc = b_lin[p];
    #pragma unroll 4
    for (int kk = 0; kk < Hz; ++kk)
      acc += bf2f(hb[kk]) * wr[kk];
    out[(gbase + b) * Pz + p] = acc;
  }
}

extern "C" void kernel_launch(void* const* d_in, const int* in_sizes, int n_in,
                              void* d_out, int out_size, void* d_ws, size_t ws_size,
                              hipStream_t stream) {
  const float* x     = (const float*)d_in[0];
  const float* w_ih0 = (const float*)d_in[1];
  const float* w_hh0 = (const float*)d_in[2];
  const float* b_ih0 = (const float*)d_in[3];
  const float* b_hh0 = (const float*)d_in[4];
  const float* w_ih1 = (const float*)d_in[5];
  const float* w_hh1 = (const float*)d_in[6];
  const float* b_ih1 = (const float*)d_in[7];
  const float* b_hh1 = (const float*)d_in[8];
  const float* w_lin = (const float*)d_in[9];
  const float* b_lin = (const float*)d_in[10];
  float* out = (float*)d_out;

  size_t lds_bytes = (size_t)(4 * HB) * 2        // h0+h1, both parities
                   + (size_t)(BT * XS) * 4       // x preload
                   + (size_t)(Pz * Hz) * 4;      // w_lin
  hipFuncSetAttribute((const void*)lstm2,
                      hipFuncAttributeMaxDynamicSharedMemorySize, (int)lds_bytes);
  lstm2<<<NG, 1024, lds_bytes, stream>>>(x, w_ih0, w_hh0, b_ih0, b_hh0,
                                         w_ih1, w_hh1, b_ih1, b_hh1,
                                         w_lin, b_lin, out);
}

// Round 4
// 1234.958 us; speedup vs baseline: 8.8418x; 8.8418x over previous
//
#include <hip/hip_runtime.h>

// Problem constants
constexpr int Bz = 512;   // batch
constexpr int Tz = 256;   // seq len
constexpr int Hz = 256;   // hidden
constexpr int Pz = 14;    // predict dim
constexpr int GB = 32;    // batch groups
constexpr int GS = 8;     // hidden slices per group
constexpr int BT = 16;    // batch per group (512/32)
constexpr int KP = 264;   // LDS h row stride (shorts)
constexpr int XS = 260;   // x LDS row stride (floats)

typedef short s8v __attribute__((ext_vector_type(8)));
typedef float f4v __attribute__((ext_vector_type(4)));
typedef unsigned long long u64;

__device__ __forceinline__ short f2bf(float f) {
  unsigned u = __float_as_uint(f);
  u = (u + 0x7fffu + ((u >> 16) & 1u)) >> 16;   // RNE
  return (short)u;
}
__device__ __forceinline__ float bf2f(short s) {
  return __uint_as_float(((unsigned)(unsigned short)s) << 16);
}
__device__ __forceinline__ float sigm(float v) { return 1.0f / (1.0f + __expf(-v)); }
__device__ __forceinline__ float tanh_f(float v) { return 1.0f - 2.0f / (__expf(2.0f * v) + 1.0f); }

__device__ __forceinline__ u64 llc_load64(const u64* p) {
  return __hip_atomic_load(p, __ATOMIC_RELAXED, __HIP_MEMORY_SCOPE_AGENT);
}
__device__ __forceinline__ unsigned llc_load32(const unsigned* p) {
  return __hip_atomic_load(p, __ATOMIC_RELAXED, __HIP_MEMORY_SCOPE_AGENT);
}
__device__ __forceinline__ void llc_store32(unsigned* p, unsigned v) {
  __hip_atomic_store(p, v, __ATOMIC_RELAXED, __HIP_MEMORY_SCOPE_AGENT);
}

// R13 = R9 (800us proven) with PER-WAVE completion flags:
//   - 32 flags/group (8 slices x 4 waves), one 128B span.
//   - producer wave: data stores (agent sc1) -> its OWN s_waitcnt vmcnt(0)
//     (drains that wave's stores to LLC AND proves its prior stage loads
//     returned) -> lane0 stores flags[g][sl*4+w] = s+1. No end-of-step
//     barrier, no block-wide drain, no tid0 serialization.
//   - consumer: all waves poll the 32 flags (lane&31) via relaxed agent
//     loads + __ballot; proceed when all >= s.
// Safety (per-wave version of the R9/R5-proven argument): poll(s) passing
// => every wave of every peer block has flag >= s => that wave completed
// step s-1 in program order: stage loads(s-1) returned (before sync1(s-1))
// -> MFMA(s-1) -> stores(s-1) -> vmcnt(0) -> flag. Hence (a) all parity
// reads of the slot I overwrite at step s are done (WAR safe), and (b) all
// step-s-1 data is at the LLC before any consumer's poll(s) passes (RAW
// safe). Barriers per step: ONE (sync1, LDS stage visibility).
// flag = #completed steps, so memset(0) initializes everything (bf16 zeros
// == t<0 hidden state).
__global__ void __launch_bounds__(256, 1)
lstm2(const float* __restrict__ x,
      const float* __restrict__ w_ih0, const float* __restrict__ w_hh0,
      const float* __restrict__ b_ih0, const float* __restrict__ b_hh0,
      const float* __restrict__ w_ih1, const float* __restrict__ w_hh1,
      const float* __restrict__ b_ih1, const float* __restrict__ b_hh1,
      const float* __restrict__ w_lin, const float* __restrict__ b_lin,
      float* __restrict__ out,
      unsigned* __restrict__ h0g, unsigned* __restrict__ h1g,
      unsigned* __restrict__ flags)
{
  const int blk  = blockIdx.x;
  const int g    = blk >> 3;      // batch group (32)
  const int sl   = blk & 7;       // hidden slice (8)
  const int tid  = threadIdx.x;
  const int w    = tid >> 6;      // wave
  const int lane = tid & 63;
  const int q    = lane >> 4;
  const int l15  = lane & 15;     // batch within group
  const int gbase = g * BT;

  extern __shared__ char smem_raw[];
  short* h0s = (short*)smem_raw;          // [BT][KP] staged h0[s-1], kpos order
  short* h1s = h0s + BT * KP;             // [BT][KP] staged h1[s-2]
  float* xls = (float*)(h1s + BT * KP);   // [BT][XS] x preload
  float* wls = xls + BT * XS;             // [Pz][256] w_lin permuted to kpos order

  // ---- one-time: weights -> register A-fragments (permuted k gather) ----
  // kpos = sl*32 + w*8 + q*2 + j  <->  k_true = sl*32 + w*4 + q + 16*j
  s8v Wf[3][2][8];   // [mat: hh0, ih1, hh1][mti][kt]
  {
    const float* wsrc[3] = {w_hh0, w_ih1, w_hh1};
    #pragma unroll
    for (int mat = 0; mat < 3; ++mat) {
      #pragma unroll
      for (int mti = 0; mti < 2; ++mti) {
        int rr = (w + mti * 4) * 16 + l15;          // rr = unit*4+gate
        int grow = (rr & 3) * Hz + sl * 32 + (rr >> 2);
        const float* p = wsrc[mat] + (size_t)grow * Hz;
        #pragma unroll
        for (int kt = 0; kt < 8; ++kt) {
          s8v f;
          #pragma unroll
          for (int j = 0; j < 8; ++j) {
            int ktrue = kt * 32 + q * 4 + (j >> 1) + 16 * (j & 1);
            f[j] = f2bf(p[ktrue]);
          }
          Wf[mat][mti][kt] = f;
        }
      }
    }
  }
  // per-lane epilogue constants: units uA = w*4+q, uB = 16+uA; gates r=0..3
  const int uA = w * 4 + q, uB = 16 + w * 4 + q;
  float wihA[4], wihB[4], b0A[4], b0B[4], b1A[4], b1B[4];
  #pragma unroll
  for (int r = 0; r < 4; ++r) {
    int ga_ = r * Hz + sl * 32 + uA;
    int gb_ = r * Hz + sl * 32 + uB;
    wihA[r] = w_ih0[ga_];              wihB[r] = w_ih0[gb_];
    b0A[r]  = b_ih0[ga_] + b_hh0[ga_]; b0B[r]  = b_ih0[gb_] + b_hh0[gb_];
    b1A[r]  = b_ih1[ga_] + b_hh1[ga_]; b1B[r]  = b_ih1[gb_] + b_hh1[gb_];
  }
  float c0A = 0.f, c0B = 0.f, c1A = 0.f, c1B = 0.f;   // cell states in VGPRs

  // ---- preload x (this group's 16 batches) and permuted w_lin (head) ----
  for (int i = tid; i < BT * (Tz / 4); i += 256) {
    int b = i >> 6, c4 = i & 63;
    f4v v = *(const f4v*)(x + (size_t)(gbase + b) * Tz + c4 * 4);
    *(f4v*)(xls + b * XS + c4 * 4) = v;
  }
  if (sl == 0) {
    for (int i = tid; i < Pz * Hz; i += 256) {
      int p = i >> 8, kpos = i & 255;
      int sl2 = kpos >> 5, w2 = (kpos >> 3) & 3, q2 = (kpos >> 1) & 3, jj = kpos & 1;
      wls[i] = w_lin[p * Hz + sl2 * 32 + w2 * 4 + q2 + 16 * jj];
    }
  }

  const unsigned* myflags = flags + g * 32 + (lane & 31);  // all 32 wave-flags
  unsigned* myflag = flags + g * 32 + sl * 4 + w;          // this wave's flag

  for (int s = 0; s <= Tz; ++s) {
    // ---- A: all-wave poll: all 32 producer waves completed step s-1 ----
    {
      const unsigned expd = (unsigned)s;
      unsigned f = llc_load32(myflags);
      while (__ballot(f >= expd) != ~0ull) {
        __builtin_amdgcn_s_sleep(1);
        f = llc_load32(myflags);
      }
    }

    // ---- B: stage h0[s-1] (parity (s+1)&1) and h1[s-2] (parity s&1) ----
    {
      const u64* s0 = (const u64*)h0g + (size_t)((s + 1) & 1) * 32768;
      const u64* s1 = (const u64*)h1g + (size_t)(s & 1) * 32768;
      u64 r0[4], r1[4];
      #pragma unroll
      for (int k = 0; k < 4; ++k) {
        int i = tid + k * 256;
        int c = i & 1, b = (i >> 1) & 15, slw = i >> 5;
        size_t gi = ((size_t)slw * Bz + gbase + b) * 2 + c;
        r0[k] = llc_load64(s0 + gi);
        r1[k] = llc_load64(s1 + gi);
      }
      #pragma unroll
      for (int k = 0; k < 4; ++k) {
        int i = tid + k * 256;
        int c = i & 1, b = (i >> 1) & 15, slw = i >> 5;
        *(u64*)(h0s + b * KP + slw * 8 + c * 4) = r0[k];
        *(u64*)(h1s + b * KP + slw * 8 + c * 4) = r1[k];
      }
    }
    __syncthreads();   // sync1: staged LDS visible (ONLY barrier per step)

    // ---- C: fused MFMA (L0: 16, L1: 32); weights from regs; 16 b128 reads ----
    f4v a0A = {0.f,0.f,0.f,0.f}, a0B = {0.f,0.f,0.f,0.f};
    f4v a1A = {0.f,0.f,0.f,0.f}, a1B = {0.f,0.f,0.f,0.f};
    const short* H0f = h0s + l15 * KP + q * 8;
    const short* H1f = h1s + l15 * KP + q * 8;
    #pragma unroll
    for (int kt = 0; kt < 8; ++kt) {
      s8v h0v = *(const s8v*)(H0f + kt * 32);
      s8v h1v = *(const s8v*)(H1f + kt * 32);
      a0A = __builtin_amdgcn_mfma_f32_16x16x32_bf16(Wf[0][0][kt], h0v, a0A, 0, 0, 0);
      a0B = __builtin_amdgcn_mfma_f32_16x16x32_bf16(Wf[0][1][kt], h0v, a0B, 0, 0, 0);
      a1A = __builtin_amdgcn_mfma_f32_16x16x32_bf16(Wf[1][0][kt], h0v, a1A, 0, 0, 0);
      a1B = __builtin_amdgcn_mfma_f32_16x16x32_bf16(Wf[1][1][kt], h0v, a1B, 0, 0, 0);
      a1A = __builtin_amdgcn_mfma_f32_16x16x32_bf16(Wf[2][0][kt], h1v, a1A, 0, 0, 0);
      a1B = __builtin_amdgcn_mfma_f32_16x16x32_bf16(Wf[2][1][kt], h1v, a1B, 0, 0, 0);
    }

    // ---- D: in-register epilogues -> one packed u32 per lane per layer ----
    unsigned pk0 = 0, pk1 = 0;
    if (s < Tz) {
      float xv = xls[l15 * XS + s];
      float iA = sigm  (a0A[0] + xv * wihA[0] + b0A[0]);
      float fA = sigm  (a0A[1] + xv * wihA[1] + b0A[1]);
      float gA = tanh_f(a0A[2] + xv * wihA[2] + b0A[2]);
      float oA = sigm  (a0A[3] + xv * wihA[3] + b0A[3]);
      c0A = fA * c0A + iA * gA;
      float iB = sigm  (a0B[0] + xv * wihB[0] + b0B[0]);
      float fB = sigm  (a0B[1] + xv * wihB[1] + b0B[1]);
      float gB = tanh_f(a0B[2] + xv * wihB[2] + b0B[2]);
      float oB = sigm  (a0B[3] + xv * wihB[3] + b0B[3]);
      c0B = fB * c0B + iB * gB;
      pk0 = (unsigned)(unsigned short)f2bf(oA * tanh_f(c0A))
          | ((unsigned)(unsigned short)f2bf(oB * tanh_f(c0B)) << 16);
    }
    if (s >= 1) {
      float iA = sigm  (a1A[0] + b1A[0]);
      float fA = sigm  (a1A[1] + b1A[1]);
      float gA = tanh_f(a1A[2] + b1A[2]);
      float oA = sigm  (a1A[3] + b1A[3]);
      c1A = fA * c1A + iA * gA;
      float iB = sigm  (a1B[0] + b1B[0]);
      float fB = sigm  (a1B[1] + b1B[1]);
      float gB = tanh_f(a1B[2] + b1B[2]);
      float oB = sigm  (a1B[3] + b1B[3]);
      c1B = fB * c1B + iB * gB;
      pk1 = (unsigned)(unsigned short)f2bf(oA * tanh_f(c1A))
          | ((unsigned)(unsigned short)f2bf(oB * tanh_f(c1B)) << 16);
    }

    // ---- E: coalesced permuted data stores (agent scope) ----
    {
      size_t base = (size_t)(sl * 4 + w) * 2048 + (size_t)(gbase + l15) * 4 + q;
      if (s < Tz)
        llc_store32(h0g + (size_t)(s & 1) * 65536 + base, pk0);
      if (s >= 1)
        llc_store32(h1g + (size_t)((s - 1) & 1) * 65536 + base, pk1);
    }

    // ---- F: per-wave drain + per-wave flag (no barrier) ----
    asm volatile("s_waitcnt vmcnt(0)" ::: "memory");
    __builtin_amdgcn_sched_barrier(0);
    if (lane == 0)
      llc_store32(myflag, (unsigned)(s + 1));
  }

  // ---- final head (sl==0 blocks): out = h1[T-1] @ w_lin^T + b_lin ----
  if (sl == 0) {
    {
      const unsigned expd = (unsigned)(Tz + 1);
      unsigned f = llc_load32(myflags);
      while (__ballot(f >= expd) != ~0ull) {
        __builtin_amdgcn_s_sleep(1);
        f = llc_load32(myflags);
      }
    }
    const u64* s1 = (const u64*)h1g + (size_t)((Tz - 1) & 1) * 32768;
    for (int k = 0; k < 4; ++k) {
      int i = tid + k * 256;
      int c = i & 1, b = (i >> 1) & 15, slw = i >> 5;
      u64 v = llc_load64(s1 + ((size_t)slw * Bz + gbase + b) * 2 + c);
      *(u64*)(h0s + b * KP + slw * 8 + c * 4) = v;
    }
    __syncthreads();
    for (int i = tid; i < BT * Pz; i += 256) {
      int b = i / Pz, p = i - b * Pz;
      const float* wr = wls + p * Hz;
      float acc = b_lin[p];
      for (int kk = 0; kk < Hz; ++kk)
        acc += bf2f(h0s[b * KP + kk]) * wr[kk];   // both in kpos order
      out[(gbase + b) * Pz + p] = acc;
    }
  }
}

extern "C" void kernel_launch(void* const* d_in, const int* in_sizes, int n_in,
                              void* d_out, int out_size, void* d_ws, size_t ws_size,
                              hipStream_t stream) {
  const float* x     = (const float*)d_in[0];
  const float* w_ih0 = (const float*)d_in[1];
  const float* w_hh0 = (const float*)d_in[2];
  const float* b_ih0 = (const float*)d_in[3];
  const float* b_hh0 = (const float*)d_in[4];
  const float* w_ih1 = (const float*)d_in[5];
  const float* w_hh1 = (const float*)d_in[6];
  const float* b_ih1 = (const float*)d_in[7];
  const float* b_hh1 = (const float*)d_in[8];
  const float* w_lin = (const float*)d_in[9];
  const float* b_lin = (const float*)d_in[10];
  float* out = (float*)d_out;

  unsigned char* ws = (unsigned char*)d_ws;
  unsigned* h0g   = (unsigned*)ws;                     // [2][65536] u32 (256 KB/parity)
  unsigned* h1g   = (unsigned*)(ws + (512 << 10));     // [2][65536] u32
  unsigned* flags = (unsigned*)(ws + (1024 << 10));    // [32 groups][32] u32 (all used)
  // memset(0): h data zeros (bf16 0x0000 = initial hidden state) + flags = 0
  // ("0 steps completed") -- no init kernel needed.
  hipMemsetAsync(d_ws, 0, (1024 << 10) + 4096, stream);

  size_t lds_bytes = (size_t)(2 * BT) * KP * 2     // h staging
                   + (size_t)(BT * XS) * 4         // x preload
                   + (size_t)(Pz * Hz) * 4;        // permuted w_lin (head)
  hipFuncSetAttribute((const void*)lstm2,
                      hipFuncAttributeMaxDynamicSharedMemorySize, (int)lds_bytes);
  lstm2<<<GB * GS, 256, lds_bytes, stream>>>(x, w_ih0, w_hh0, b_ih0, b_hh0,
                                             w_ih1, w_hh1, b_ih1, b_hh1,
                                             w_lin, b_lin, out, h0g, h1g, flags);
}

// Round 5
// 727.459 us; speedup vs baseline: 15.0101x; 1.6976x over previous
//
#include <hip/hip_runtime.h>

// Problem constants
constexpr int Bz = 512;   // batch
constexpr int Tz = 256;   // seq len
constexpr int Hz = 256;   // hidden
constexpr int Pz = 14;    // predict dim
constexpr int GB = 32;    // batch groups
constexpr int GS = 8;     // hidden slices per group
constexpr int BT = 16;    // batch per group (512/32)
constexpr int KP = 264;   // LDS h row stride (shorts)
constexpr int XS = 260;   // x LDS row stride (floats)

typedef short s8v __attribute__((ext_vector_type(8)));
typedef float f4v __attribute__((ext_vector_type(4)));
typedef unsigned long long u64;

__device__ __forceinline__ short f2bf(float f) {
  unsigned u = __float_as_uint(f);
  u = (u + 0x7fffu + ((u >> 16) & 1u)) >> 16;   // RNE
  return (short)u;
}
__device__ __forceinline__ float bf2f(short s) {
  return __uint_as_float(((unsigned)(unsigned short)s) << 16);
}
// Fast gates (R11-proven numerics: passed with identical absmax 4.88e-4).
// v_exp_f32 IS exp2; v_rcp_f32 replaces the f32 divide sequence.
__device__ __forceinline__ float sigm(float v) {
  return __builtin_amdgcn_rcpf(1.0f + __builtin_amdgcn_exp2f(-1.442695041f * v));
}
__device__ __forceinline__ float tanh_f(float v) {
  return 1.0f - 2.0f * __builtin_amdgcn_rcpf(__builtin_amdgcn_exp2f(2.885390082f * v) + 1.0f);
}

__device__ __forceinline__ u64 llc_load64(const u64* p) {
  return __hip_atomic_load(p, __ATOMIC_RELAXED, __HIP_MEMORY_SCOPE_AGENT);
}
__device__ __forceinline__ unsigned llc_load32(const unsigned* p) {
  return __hip_atomic_load(p, __ATOMIC_RELAXED, __HIP_MEMORY_SCOPE_AGENT);
}
__device__ __forceinline__ void llc_store32(unsigned* p, unsigned v) {
  __hip_atomic_store(p, v, __ATOMIC_RELAXED, __HIP_MEMORY_SCOPE_AGENT);
}
__device__ __forceinline__ void llc_store64(u64* p, u64 v) {
  __hip_atomic_store(p, v, __ATOMIC_RELAXED, __HIP_MEMORY_SCOPE_AGENT);
}

// R14 = R9 (800us proven protocol: block barrier + single tid0 publisher,
// 8 flags/group — R13 showed per-wave publishes cause flag-line contention)
// with three safe deltas:
//  1. COMBINED h word: h0[s] and h1[s-1] are both produced at iter s ->
//     one u64 store per lane into a single array at parity s&1.
//     (pk1=0 at s=0 IS the correct h1[-1]=0; pk0=0 at s=Tz is never read.)
//     Halves producer stores; drain waits on 1 outstanding store.
//  2. Wave0-only poll (+barrier): 4x less machine-wide poll traffic.
//  3. Fast gates (rcp+exp2) shorten the serial epilogue.
// Safety argument identical to R9: poll(s) pass => every peer block's tid0
// published s-1 => that block passed its F-barrier => all its waves drained
// vmcnt(0) => its iter-s-1 data is at LLC AND its iter-s-1 stage loads
// returned => parity overwrite at iter s is WAR/RAW safe.
__global__ void __launch_bounds__(256, 1)
lstm2(const float* __restrict__ x,
      const float* __restrict__ w_ih0, const float* __restrict__ w_hh0,
      const float* __restrict__ b_ih0, const float* __restrict__ b_hh0,
      const float* __restrict__ w_ih1, const float* __restrict__ w_hh1,
      const float* __restrict__ b_ih1, const float* __restrict__ b_hh1,
      const float* __restrict__ w_lin, const float* __restrict__ b_lin,
      float* __restrict__ out,
      u64* __restrict__ hg, unsigned* __restrict__ flags)
{
  const int blk  = blockIdx.x;
  const int g    = blk >> 3;      // batch group (32)
  const int sl   = blk & 7;       // hidden slice (8)
  const int tid  = threadIdx.x;
  const int w    = tid >> 6;      // wave
  const int lane = tid & 63;
  const int q    = lane >> 4;
  const int l15  = lane & 15;     // batch within group
  const int gbase = g * BT;

  extern __shared__ char smem_raw[];
  short* h0s = (short*)smem_raw;          // [BT][KP] staged h0[s-1], kpos order
  short* h1s = h0s + BT * KP;             // [BT][KP] staged h1[s-2]
  float* xls = (float*)(h1s + BT * KP);   // [BT][XS] x preload
  float* wls = xls + BT * XS;             // [Pz][256] w_lin permuted to kpos order

  // ---- one-time: weights -> register A-fragments (permuted k gather) ----
  // kpos = sl*32 + w*8 + q*2 + j  <->  k_true = sl*32 + w*4 + q + 16*j
  s8v Wf[3][2][8];   // [mat: hh0, ih1, hh1][mti][kt]
  {
    const float* wsrc[3] = {w_hh0, w_ih1, w_hh1};
    #pragma unroll
    for (int mat = 0; mat < 3; ++mat) {
      #pragma unroll
      for (int mti = 0; mti < 2; ++mti) {
        int rr = (w + mti * 4) * 16 + l15;          // rr = unit*4+gate
        int grow = (rr & 3) * Hz + sl * 32 + (rr >> 2);
        const float* p = wsrc[mat] + (size_t)grow * Hz;
        #pragma unroll
        for (int kt = 0; kt < 8; ++kt) {
          s8v f;
          #pragma unroll
          for (int j = 0; j < 8; ++j) {
            int ktrue = kt * 32 + q * 4 + (j >> 1) + 16 * (j & 1);
            f[j] = f2bf(p[ktrue]);
          }
          Wf[mat][mti][kt] = f;
        }
      }
    }
  }
  // per-lane epilogue constants: units uA = w*4+q, uB = 16+uA; gates r=0..3
  const int uA = w * 4 + q, uB = 16 + w * 4 + q;
  float wihA[4], wihB[4], b0A[4], b0B[4], b1A[4], b1B[4];
  #pragma unroll
  for (int r = 0; r < 4; ++r) {
    int ga_ = r * Hz + sl * 32 + uA;
    int gb_ = r * Hz + sl * 32 + uB;
    wihA[r] = w_ih0[ga_];              wihB[r] = w_ih0[gb_];
    b0A[r]  = b_ih0[ga_] + b_hh0[ga_]; b0B[r]  = b_ih0[gb_] + b_hh0[gb_];
    b1A[r]  = b_ih1[ga_] + b_hh1[ga_]; b1B[r]  = b_ih1[gb_] + b_hh1[gb_];
  }
  float c0A = 0.f, c0B = 0.f, c1A = 0.f, c1B = 0.f;   // cell states in VGPRs

  // ---- preload x (this group's 16 batches) and permuted w_lin (head) ----
  for (int i = tid; i < BT * (Tz / 4); i += 256) {
    int b = i >> 6, c4 = i & 63;
    f4v v = *(const f4v*)(x + (size_t)(gbase + b) * Tz + c4 * 4);
    *(f4v*)(xls + b * XS + c4 * 4) = v;
  }
  if (sl == 0) {
    for (int i = tid; i < Pz * Hz; i += 256) {
      int p = i >> 8, kpos = i & 255;
      int sl2 = kpos >> 5, w2 = (kpos >> 3) & 3, q2 = (kpos >> 1) & 3, jj = kpos & 1;
      wls[i] = w_lin[p * Hz + sl2 * 32 + w2 * 4 + q2 + 16 * jj];
    }
  }

  const unsigned* myflags = flags + g * 32 + (lane & 7);  // group's 8 flags, one line
  unsigned* myflag = flags + g * 32 + sl;

  for (int s = 0; s <= Tz; ++s) {
    // ---- A: wave0 polls: all 8 producers completed step s-1; barrier gates rest ----
    if (w == 0) {
      const unsigned expd = (unsigned)s;
      unsigned f = llc_load32(myflags);
      while (__ballot(f >= expd) != ~0ull) {
        __builtin_amdgcn_s_sleep(1);
        f = llc_load32(myflags);
      }
    }
    __syncthreads();   // barrier A: poll verdict gates all waves' stage loads

    // ---- B: stage combined words from parity (s+1)&1 = (s-1)&1 ----
    // word (slw, b, q) = lo32: h0 pair (uA,uB) | hi32: h1 pair, iter s-1
    {
      const u64* sp = hg + (size_t)((s + 1) & 1) * 65536;
      u64 r[8];
      #pragma unroll
      for (int k = 0; k < 4; ++k) {
        int i = tid + k * 256;
        int c = i & 1, b = (i >> 1) & 15, slw = i >> 5;
        size_t gi = ((size_t)slw * Bz + gbase + b) * 4 + 2 * c;
        r[2 * k]     = llc_load64(sp + gi);
        r[2 * k + 1] = llc_load64(sp + gi + 1);
      }
      #pragma unroll
      for (int k = 0; k < 4; ++k) {
        int i = tid + k * 256;
        int c = i & 1, b = (i >> 1) & 15, slw = i >> 5;
        u64 lo = r[2 * k], hi = r[2 * k + 1];
        *(u64*)(h0s + b * KP + slw * 8 + c * 4) =
            (u64)(unsigned)lo | ((u64)(unsigned)hi << 32);
        *(u64*)(h1s + b * KP + slw * 8 + c * 4) =
            (lo >> 32) | ((hi >> 32) << 32);
      }
    }
    __syncthreads();   // sync1: staged LDS visible

    // ---- C: fused MFMA (L0: 16, L1: 32); weights from regs; 16 b128 reads ----
    f4v a0A = {0.f,0.f,0.f,0.f}, a0B = {0.f,0.f,0.f,0.f};
    f4v a1A = {0.f,0.f,0.f,0.f}, a1B = {0.f,0.f,0.f,0.f};
    const short* H0f = h0s + l15 * KP + q * 8;
    const short* H1f = h1s + l15 * KP + q * 8;
    #pragma unroll
    for (int kt = 0; kt < 8; ++kt) {
      s8v h0v = *(const s8v*)(H0f + kt * 32);
      s8v h1v = *(const s8v*)(H1f + kt * 32);
      a0A = __builtin_amdgcn_mfma_f32_16x16x32_bf16(Wf[0][0][kt], h0v, a0A, 0, 0, 0);
      a0B = __builtin_amdgcn_mfma_f32_16x16x32_bf16(Wf[0][1][kt], h0v, a0B, 0, 0, 0);
      a1A = __builtin_amdgcn_mfma_f32_16x16x32_bf16(Wf[1][0][kt], h0v, a1A, 0, 0, 0);
      a1B = __builtin_amdgcn_mfma_f32_16x16x32_bf16(Wf[1][1][kt], h0v, a1B, 0, 0, 0);
      a1A = __builtin_amdgcn_mfma_f32_16x16x32_bf16(Wf[2][0][kt], h1v, a1A, 0, 0, 0);
      a1B = __builtin_amdgcn_mfma_f32_16x16x32_bf16(Wf[2][1][kt], h1v, a1B, 0, 0, 0);
    }

    // ---- D: in-register epilogues -> one packed u32 per layer ----
    unsigned pk0 = 0, pk1 = 0;
    if (s < Tz) {
      float xv = xls[l15 * XS + s];
      float iA = sigm  (a0A[0] + xv * wihA[0] + b0A[0]);
      float fA = sigm  (a0A[1] + xv * wihA[1] + b0A[1]);
      float gA = tanh_f(a0A[2] + xv * wihA[2] + b0A[2]);
      float oA = sigm  (a0A[3] + xv * wihA[3] + b0A[3]);
      c0A = fA * c0A + iA * gA;
      float iB = sigm  (a0B[0] + xv * wihB[0] + b0B[0]);
      float fB = sigm  (a0B[1] + xv * wihB[1] + b0B[1]);
      float gB = tanh_f(a0B[2] + xv * wihB[2] + b0B[2]);
      float oB = sigm  (a0B[3] + xv * wihB[3] + b0B[3]);
      c0B = fB * c0B + iB * gB;
      pk0 = (unsigned)(unsigned short)f2bf(oA * tanh_f(c0A))
          | ((unsigned)(unsigned short)f2bf(oB * tanh_f(c0B)) << 16);
    }
    if (s >= 1) {
      float iA = sigm  (a1A[0] + b1A[0]);
      float fA = sigm  (a1A[1] + b1A[1]);
      float gA = tanh_f(a1A[2] + b1A[2]);
      float oA = sigm  (a1A[3] + b1A[3]);
      c1A = fA * c1A + iA * gA;
      float iB = sigm  (a1B[0] + b1B[0]);
      float fB = sigm  (a1B[1] + b1B[1]);
      float gB = tanh_f(a1B[2] + b1B[2]);
      float oB = sigm  (a1B[3] + b1B[3]);
      c1B = fB * c1B + iB * gB;
      pk1 = (unsigned)(unsigned short)f2bf(oA * tanh_f(c1A))
          | ((unsigned)(unsigned short)f2bf(oB * tanh_f(c1B)) << 16);
    }

    // ---- E: ONE combined coalesced store (unconditional) ----
    // pk1=0 at s=0 is the true h1[-1]=0; pk0=0 at s=Tz is never read.
    {
      size_t base = (size_t)(sl * 4 + w) * 2048 + (size_t)(gbase + l15) * 4 + q;
      llc_store64(hg + (size_t)(s & 1) * 65536 + base,
                  (u64)pk0 | ((u64)pk1 << 32));
    }

    // ---- F: drain (per-wave vmcnt(0) inside __syncthreads) + publish ----
    __syncthreads();
    if (tid == 0)
      llc_store32(myflag, (unsigned)(s + 1));
  }

  // ---- final head (sl==0 blocks): out = h1[Tz-1] @ w_lin^T + b_lin ----
  // h1[Tz-1] = hi32 halves of combined words written at iter Tz, parity 0.
  if (sl == 0) {
    {
      const unsigned expd = (unsigned)(Tz + 1);
      unsigned f = llc_load32(myflags);
      while (__ballot(f >= expd) != ~0ull) {
        __builtin_amdgcn_s_sleep(1);
        f = llc_load32(myflags);
      }
    }
    const u64* sp = hg + (size_t)(Tz & 1) * 65536;   // parity 0
    for (int k = 0; k < 4; ++k) {
      int i = tid + k * 256;
      int c = i & 1, b = (i >> 1) & 15, slw = i >> 5;
      size_t gi = ((size_t)slw * Bz + gbase + b) * 4 + 2 * c;
      u64 lo = llc_load64(sp + gi);
      u64 hi = llc_load64(sp + gi + 1);
      *(u64*)(h0s + b * KP + slw * 8 + c * 4) = (lo >> 32) | ((hi >> 32) << 32);
    }
    __syncthreads();
    for (int i = tid; i < BT * Pz; i += 256) {
      int b = i / Pz, p = i - b * Pz;
      const float* wr = wls + p * Hz;
      float acc = b_lin[p];
      for (int kk = 0; kk < Hz; ++kk)
        acc += bf2f(h0s[b * KP + kk]) * wr[kk];   // both in kpos order
      out[(gbase + b) * Pz + p] = acc;
    }
  }
}

extern "C" void kernel_launch(void* const* d_in, const int* in_sizes, int n_in,
                              void* d_out, int out_size, void* d_ws, size_t ws_size,
                              hipStream_t stream) {
  const float* x     = (const float*)d_in[0];
  const float* w_ih0 = (const float*)d_in[1];
  const float* w_hh0 = (const float*)d_in[2];
  const float* b_ih0 = (const float*)d_in[3];
  const float* b_hh0 = (const float*)d_in[4];
  const float* w_ih1 = (const float*)d_in[5];
  const float* w_hh1 = (const float*)d_in[6];
  const float* b_ih1 = (const float*)d_in[7];
  const float* b_hh1 = (const float*)d_in[8];
  const float* w_lin = (const float*)d_in[9];
  const float* b_lin = (const float*)d_in[10];
  float* out = (float*)d_out;

  unsigned char* ws = (unsigned char*)d_ws;
  u64* hg         = (u64*)ws;                          // [2][65536] u64 (512 KB/parity)
  unsigned* flags = (unsigned*)(ws + (1 << 20));       // [32 groups][32] u32 (8 used)
  // memset(0): h data zeros (bf16 0x0000 = initial hidden state) + flags = 0
  hipMemsetAsync(d_ws, 0, (1 << 20) + 4096, stream);

  size_t lds_bytes = (size_t)(2 * BT) * KP * 2     // h staging
                   + (size_t)(BT * XS) * 4         // x preload
                   + (size_t)(Pz * Hz) * 4;        // permuted w_lin (head)
  hipFuncSetAttribute((const void*)lstm2,
                      hipFuncAttributeMaxDynamicSharedMemorySize, (int)lds_bytes);
  lstm2<<<GB * GS, 256, lds_bytes, stream>>>(x, w_ih0, w_hh0, b_ih0, b_hh0,
                                             w_ih1, w_hh1, b_ih1, b_hh1,
                                             w_lin, b_lin, out, hg, flags);
}